// Round 15
// baseline (220.201 us; speedup 1.0000x reference)
//
#include <hip/hip_runtime.h>
#include <math.h>
#include <type_traits>
#include <utility>

#if defined(__has_builtin)
#if __has_builtin(__builtin_amdgcn_rcpf)
#define FAST_RCPF(x) __builtin_amdgcn_rcpf(x)
#endif
#if __has_builtin(__builtin_amdgcn_rsqf)
#define FAST_RSQF(x) __builtin_amdgcn_rsqf(x)
#endif
#endif
#ifndef FAST_RCPF
#define FAST_RCPF(x) (1.0f / (x))
#endif
#ifndef FAST_RSQF
#define FAST_RSQF(x) (1.0f / sqrtf(x))
#endif

// packed lower-tri index (constexpr -> folds in templates)
__host__ __device__ constexpr int PIX(int i, int j) { return i * (i + 1) / 2 + j; }

// moment-pattern helpers: 6 patterns of (e1,e2), e1+e2<=2
// 0:(0,0) 1:(1,0) 2:(0,1) 3:(2,0) 4:(1,1) 5:(0,2)
__host__ __device__ constexpr int E1(int k) { return k == 1 ? 1 : k == 3 ? 2 : k == 4 ? 1 : 0; }
__host__ __device__ constexpr int E2(int k) { return k == 2 ? 1 : k == 4 ? 1 : k == 5 ? 2 : 0; }
__host__ __device__ constexpr int EIDX(int i, int j) {
  return (i == 0 && j == 0) ? 0 : (i == 1 && j == 0) ? 1 : (i == 0 && j == 1) ? 2
       : (i == 2 && j == 0) ? 3 : (i == 1 && j == 1) ? 4 : 5;
}
__host__ __device__ constexpr double BIN(int n, int k) { return (n == 2 && k == 1) ? 2.0 : 1.0; }
template <int P>
__device__ __forceinline__ double ipw(double x) {
  if constexpr (P <= 0) return 1.0;
  else return x * ipw<P - 1>(x);
}

// ============================================================
// static_for: source-level unrolling. RULE (R6/R7): SROA runs BEFORE loop
// unrolling and never re-runs -> template recursion emits literal-constant
// indices so the first SROA pass promotes allocas to registers.
// RULE (R9/R11): a kernel holding 45 per-thread accumulator doubles must be
// dedicated+simple or the allocator spills it. (This round removes that
// accumulator from the streaming path entirely -- raw-moment trick.)
// RULE (R13): no mixed packed/scalar f32 dataflow (LDS spill).
// RULE (R14): sampson's 65% VALUBusy is not occupancy-bound; 4 models/block
// is the sweet spot.
// ============================================================
template <int N, int I = 0, typename F>
__device__ __forceinline__ void static_for(F&& f) {
  if constexpr (I < N) {
    f(std::integral_constant<int, I>{});
    static_for<N, I + 1>(static_cast<F&&>(f));
  }
}

// ---------- 9x9 packed Cholesky, template-indexed ----------
template <int I, int J, int K>
__device__ __forceinline__ double csub9(const double* M, double s) {
  if constexpr (K >= J) return s;
  else return csub9<I, J, K + 1>(M, s - M[PIX(I, K)] * M[PIX(J, K)]);
}
template <int I, int J>
__device__ __forceinline__ void cholJ(double* M) {
  if constexpr (J <= I) {
    double s = csub9<I, J, 0>(M, M[PIX(I, J)]);
    if constexpr (J == I)
      M[PIX(I, I)] = sqrt(fmax(s, 1e-300));
    else
      M[PIX(I, J)] = s / M[PIX(J, J)];
    cholJ<I, J + 1>(M);
  }
}
template <int I>
__device__ __forceinline__ void cholI(double* M) {
  if constexpr (I < 9) {
    cholJ<I, 0>(M);
    cholI<I + 1>(M);
  }
}

// ---------- forward/backward substitution, template-indexed ----------
template <int I, int K>
__device__ __forceinline__ double fsub9(const double* L, const double* x, double s) {
  if constexpr (K >= I) return s;
  else return fsub9<I, K + 1>(L, x, s - L[PIX(I, K)] * x[K]);
}
template <int I>
__device__ __forceinline__ void fwd9(const double* L, double* x) {
  if constexpr (I < 9) {
    x[I] = fsub9<I, 0>(L, x, x[I]) / L[PIX(I, I)];
    fwd9<I + 1>(L, x);
  }
}
template <int I, int K>
__device__ __forceinline__ double bsub9(const double* L, const double* x, double s) {
  if constexpr (K >= 9) return s;
  else return bsub9<I, K + 1>(L, x, s - L[PIX(K, I)] * x[K]);
}
template <int I>
__device__ __forceinline__ void bwd9(const double* L, double* x) {
  if constexpr (I >= 0) {
    x[I] = bsub9<I, I + 1>(L, x, x[I]) / L[PIX(I, I)];
    bwd9<I - 1>(L, x);
  }
}

// ---------- AtA rank-1 update (fit kernel only) ----------
template <int I, int J>
__device__ __forceinline__ void ataIJ(double* M, const double (&a)[9], double w) {
  if constexpr (J <= I) {
    M[PIX(I, J)] += w * a[I] * a[J];
    ataIJ<I, J + 1>(M, a, w);
  }
}
template <int I>
__device__ __forceinline__ void ataI(double* M, const double (&a)[9], double w) {
  if constexpr (I < 9) {
    ataIJ<I, 0>(M, a, w);
    ataI<I + 1>(M, a, w);
  }
}

// ---------- 3x3 Jacobi rotation on named scalars (no arrays at all) ----------
#define JROT(P, Q)                                                              \
  {                                                                             \
    double apq = a##P##Q;                                                       \
    if (fabs(apq) >= 1e-300) {                                                  \
      double tau = (a##Q##Q - a##P##P) / (2.0 * apq);                           \
      double t = ((tau >= 0.0) ? 1.0 : -1.0) / (fabs(tau) + sqrt(1.0 + tau * tau)); \
      double c = 1.0 / sqrt(1.0 + t * t);                                       \
      double s = t * c;                                                         \
      double t0p = a0##P, t0q = a0##Q;                                          \
      a0##P = c * t0p - s * t0q; a0##Q = s * t0p + c * t0q;                     \
      double t1p = a1##P, t1q = a1##Q;                                          \
      a1##P = c * t1p - s * t1q; a1##Q = s * t1p + c * t1q;                     \
      double t2p = a2##P, t2q = a2##Q;                                          \
      a2##P = c * t2p - s * t2q; a2##Q = s * t2p + c * t2q;                     \
      double rp0 = a##P##0, rq0 = a##Q##0;                                      \
      a##P##0 = c * rp0 - s * rq0; a##Q##0 = s * rp0 + c * rq0;                 \
      double rp1 = a##P##1, rq1 = a##Q##1;                                      \
      a##P##1 = c * rp1 - s * rq1; a##Q##1 = s * rp1 + c * rq1;                 \
      double rp2 = a##P##2, rq2 = a##Q##2;                                      \
      a##P##2 = c * rp2 - s * rq2; a##Q##2 = s * rp2 + c * rq2;                 \
      double u0p = V0##P, u0q = V0##Q;                                          \
      V0##P = c * u0p - s * u0q; V0##Q = s * u0p + c * u0q;                     \
      double u1p = V1##P, u1q = V1##Q;                                          \
      V1##P = c * u1p - s * u1q; V1##Q = s * u1p + c * u1q;                     \
      double u2p = V2##P, u2q = V2##Q;                                          \
      V2##P = c * u2p - s * u2q; V2##Q = s * u2p + c * u2q;                     \
    }                                                                           \
  }

// ---------- full solver: null vec of AtA -> rank-2 -> denormalize ----------
__device__ __forceinline__ void solveF(double* M, double s1, double m1x, double m1y,
                                       double s2, double m2x, double m2y,
                                       float* out) {
  double tr = M[0] + M[2] + M[5] + M[9] + M[14] + M[20] + M[27] + M[35] + M[44];
  double shift = 1e-12 * tr;
  M[0] += shift; M[2] += shift; M[5] += shift; M[9] += shift; M[14] += shift;
  M[20] += shift; M[27] += shift; M[35] += shift; M[44] += shift;
  cholI<0>(M);
  double x[9];
  static_for<9>([&](auto i) { x[i] = 1.0; });
  static_for<3>([&](auto) {
    fwd9<0>(M, x);
    bwd9<8>(M, x);
    double n = 0.0;
    static_for<9>([&](auto i) { n += x[i] * x[i]; });
    n = 1.0 / sqrt(n);
    static_for<9>([&](auto i) { x[i] *= n; });
  });
  const double g00 = x[0] * x[0] + x[3] * x[3] + x[6] * x[6];
  const double g01 = x[0] * x[1] + x[3] * x[4] + x[6] * x[7];
  const double g02 = x[0] * x[2] + x[3] * x[5] + x[6] * x[8];
  const double g11 = x[1] * x[1] + x[4] * x[4] + x[7] * x[7];
  const double g12 = x[1] * x[2] + x[4] * x[5] + x[7] * x[8];
  const double g22 = x[2] * x[2] + x[5] * x[5] + x[8] * x[8];
  double a00 = g00, a01 = g01, a02 = g02;
  double a10 = g01, a11 = g11, a12 = g12;
  double a20 = g02, a21 = g12, a22 = g22;
  double V00 = 1, V01 = 0, V02 = 0;
  double V10 = 0, V11 = 1, V12 = 0;
  double V20 = 0, V21 = 0, V22 = 1;
  for (int sweep = 0; sweep < 6; ++sweep) {
    JROT(0, 1);
    JROT(0, 2);
    JROT(1, 2);
  }
  double mv = a00, v0 = V00, v1 = V10, v2 = V20;
  if (a11 < mv) { mv = a11; v0 = V01; v1 = V11; v2 = V21; }
  if (a22 < mv) { mv = a22; v0 = V02; v1 = V12; v2 = V22; }
  const double fv0 = x[0] * v0 + x[1] * v1 + x[2] * v2;
  const double fv1 = x[3] * v0 + x[4] * v1 + x[5] * v2;
  const double fv2 = x[6] * v0 + x[7] * v1 + x[8] * v2;
  const double F200 = x[0] - fv0 * v0, F201 = x[1] - fv0 * v1, F202 = x[2] - fv0 * v2;
  const double F210 = x[3] - fv1 * v0, F211 = x[4] - fv1 * v1, F212 = x[5] - fv1 * v2;
  const double F220 = x[6] - fv2 * v0, F221 = x[7] - fv2 * v1, F222 = x[8] - fv2 * v2;
  const double R00 = s2 * F200, R01 = s2 * F201, R02 = s2 * F202;
  const double R10 = s2 * F210, R11 = s2 * F211, R12 = s2 * F212;
  const double R20 = -s2 * m2x * F200 - s2 * m2y * F210 + F220;
  const double R21 = -s2 * m2x * F201 - s2 * m2y * F211 + F221;
  const double R22 = -s2 * m2x * F202 - s2 * m2y * F212 + F222;
  const double Ff00 = s1 * R00, Ff01 = s1 * R01;
  const double Ff02 = -s1 * m1x * R00 - s1 * m1y * R01 + R02;
  const double Ff10 = s1 * R10, Ff11 = s1 * R11;
  const double Ff12 = -s1 * m1x * R10 - s1 * m1y * R11 + R12;
  const double Ff20 = s1 * R20, Ff21 = s1 * R21;
  const double Ff22 = -s1 * m1x * R20 - s1 * m1y * R21 + R22;
  const double inv = 1.0 / Ff22;
  out[0] = (float)(Ff00 * inv); out[1] = (float)(Ff01 * inv); out[2] = (float)(Ff02 * inv);
  out[3] = (float)(Ff10 * inv); out[4] = (float)(Ff11 * inv); out[5] = (float)(Ff12 * inv);
  out[6] = (float)(Ff20 * inv); out[7] = (float)(Ff21 * inv); out[8] = (float)(Ff22 * inv);
}

// ============================================================
// Sampson terms (z==1.0 exactly; elision is bit-identical)
// ============================================================
struct F9 {
  float f0, f1, f2, f3, f4, f5, f6, f7, f8;
};

__device__ __forceinline__ F9 loadF(const float* __restrict__ p) {
  F9 F;
  F.f0 = p[0]; F.f1 = p[1]; F.f2 = p[2];
  F.f3 = p[3]; F.f4 = p[4]; F.f5 = p[5];
  F.f6 = p[6]; F.f7 = p[7]; F.f8 = p[8];
  return F;
}

__device__ __forceinline__ void samp_numden(const F9& F, float px, float py,
                                            float qx, float qy, float& num,
                                            float& den, float& dout) {
  float a0 = fmaf(F.f0, px, fmaf(F.f1, py, F.f2));
  float a1 = fmaf(F.f3, px, fmaf(F.f4, py, F.f5));
  float a2 = fmaf(F.f6, px, fmaf(F.f7, py, F.f8));
  float b0 = fmaf(F.f0, qx, fmaf(F.f3, qy, F.f6));
  float b1 = fmaf(F.f1, qx, fmaf(F.f4, qy, F.f7));
  float d = fmaf(qx, a0, fmaf(qy, a1, a2));
  num = d * d;
  den = fmaf(a0, a0, fmaf(a1, a1, fmaf(b0, b0, b1 * b1)));
  dout = d;
}

// predicate num<=den is EXACT (same every round); sqrt(err) = |d|*rsqrt(den).
__device__ __forceinline__ void samp_acc(const F9& F, float px, float py,
                                         float qx, float qy, float& cnt,
                                         float& ss) {
  float num, den, d;
  samp_numden(F, px, py, qx, qy, num, den, d);
  const bool in = (num <= den);
  const float val = fabsf(d) * FAST_RSQF(den);
  cnt += in ? 1.0f : 0.0f;
  ss += in ? val : 0.0f;
}

// ============================================================
// Kernel 1: transpose blocks [0,TB) (float2 x,y) + fit blocks [TB,..).
// Block 0 also zeroes acc[48] + sync2.
// ============================================================
__global__ __launch_bounds__(256, 1) void prep_and_fit(
    const float* __restrict__ pts1, const float* __restrict__ pts2,
    const int* __restrict__ samples, float2* __restrict__ P1,
    float2* __restrict__ P2, float* __restrict__ models,
    int* __restrict__ uflag, double* __restrict__ acc,
    unsigned int* __restrict__ sync2, int N, int iters, int TB) {
  if ((int)blockIdx.x < TB) {
    if (blockIdx.x == 0) {
      if (threadIdx.x < 48) acc[threadIdx.x] = 0.0;
      if (threadIdx.x == 48) { sync2[0] = 0u; sync2[1] = 0u; }
    }
    const int i = blockIdx.x * 256 + threadIdx.x;
    if (i < N) {
      P1[i] = make_float2(pts1[3 * i], pts1[3 * i + 1]);
      P2[i] = make_float2(pts2[3 * i], pts2[3 * i + 1]);
    }
    return;
  }
  if (threadIdx.x >= 64) return;
  const int it = (blockIdx.x - TB) * 64 + threadIdx.x;
  if (it >= iters) return;

  int idx[8];
  static_for<8>([&](auto k) { idx[k] = samples[it * 8 + k]; });
  int u = 1;
  static_for<8>([&](auto A) {
    static_for<8>([&](auto B) {
      if constexpr (decltype(B)::value > decltype(A)::value) {
        if (idx[A] == idx[B]) u = 0;
      }
    });
  });
  uflag[it] = u;

  float X1[8], Y1[8], Z1[8], X2[8], Y2[8], Z2[8];
  static_for<8>([&](auto k) {
    const int j = idx[k];
    X1[k] = pts1[3 * j]; Y1[k] = pts1[3 * j + 1]; Z1[k] = pts1[3 * j + 2];
    X2[k] = pts2[3 * j]; Y2[k] = pts2[3 * j + 1]; Z2[k] = pts2[3 * j + 2];
  });
  double sx1 = 0, sy1 = 0, sx2 = 0, sy2 = 0;
  static_for<8>([&](auto k) {
    sx1 += (double)X1[k]; sy1 += (double)Y1[k];
    sx2 += (double)X2[k]; sy2 += (double)Y2[k];
  });
  const double m1x = sx1 / 8.0, m1y = sy1 / 8.0;
  const double m2x = sx2 / 8.0, m2y = sy2 / 8.0;
  double sd1 = 0, sd2 = 0;
  static_for<8>([&](auto k) {
    double dx1 = (double)X1[k] - m1x, dy1 = (double)Y1[k] - m1y;
    double dx2 = (double)X2[k] - m2x, dy2 = (double)Y2[k] - m2y;
    sd1 += sqrt(dx1 * dx1 + dy1 * dy1);
    sd2 += sqrt(dx2 * dx2 + dy2 * dy2);
  });
  const double s1 = sqrt(2.0) / (sd1 / 8.0 + 1e-8);
  const double s2 = sqrt(2.0) / (sd2 / 8.0 + 1e-8);

  double M[45];
  static_for<45>([&](auto r) { M[r] = 0.0; });
  static_for<8>([&](auto k) {
    const double z1 = (double)Z1[k], z2 = (double)Z2[k];
    const double p1x = s1 * ((double)X1[k] - m1x * z1);
    const double p1y = s1 * ((double)Y1[k] - m1y * z1);
    const double p2x = s2 * ((double)X2[k] - m2x * z2);
    const double p2y = s2 * ((double)Y2[k] - m2y * z2);
    const double a[9] = {p2x * p1x, p2x * p1y, p2x * z1,
                         p2y * p1x, p2y * p1y, p2y * z1,
                         z2 * p1x,  z2 * p1y,  z2 * z1};
    ataI<0>(M, a, 1.0);
  });
  solveF(M, s1, m1x, m1y, s2, m2x, m2y, models + (size_t)it * 9);
}

// ============================================================
// Kernel 2: 4 models/block (R12-proven: 43.4us), float2 loads
// ============================================================
__global__ __launch_bounds__(256, 4) void sampson_stats4(
    const float2* __restrict__ P1, const float2* __restrict__ P2,
    const float* __restrict__ models, float* __restrict__ ml,
    float* __restrict__ ssum, int N, int iters) {
  const int m0 = blockIdx.x * 4;
  const int c0 = min(m0 + 0, iters - 1), c1 = min(m0 + 1, iters - 1);
  const int c2 = min(m0 + 2, iters - 1), c3 = min(m0 + 3, iters - 1);
  const F9 Fa = loadF(models + (size_t)c0 * 9);
  const F9 Fb = loadF(models + (size_t)c1 * 9);
  const F9 Fc = loadF(models + (size_t)c2 * 9);
  const F9 Fd = loadF(models + (size_t)c3 * 9);
  float ca = 0, cb = 0, cc = 0, cd = 0;
  float sa = 0, sb = 0, sc_ = 0, sd = 0;
  const int NP = N & ~511;
  for (int i = threadIdx.x; i < NP; i += 512) {
    const float2 pA = P1[i];
    const float2 qA = P2[i];
    const float2 pB = P1[i + 256];
    const float2 qB = P2[i + 256];
    samp_acc(Fa, pA.x, pA.y, qA.x, qA.y, ca, sa);
    samp_acc(Fb, pA.x, pA.y, qA.x, qA.y, cb, sb);
    samp_acc(Fc, pA.x, pA.y, qA.x, qA.y, cc, sc_);
    samp_acc(Fd, pA.x, pA.y, qA.x, qA.y, cd, sd);
    samp_acc(Fa, pB.x, pB.y, qB.x, qB.y, ca, sa);
    samp_acc(Fb, pB.x, pB.y, qB.x, qB.y, cb, sb);
    samp_acc(Fc, pB.x, pB.y, qB.x, qB.y, cc, sc_);
    samp_acc(Fd, pB.x, pB.y, qB.x, qB.y, cd, sd);
  }
  for (int i = NP + threadIdx.x; i < N; i += 256) {
    const float2 p = P1[i];
    const float2 q = P2[i];
    samp_acc(Fa, p.x, p.y, q.x, q.y, ca, sa);
    samp_acc(Fb, p.x, p.y, q.x, q.y, cb, sb);
    samp_acc(Fc, p.x, p.y, q.x, q.y, cc, sc_);
    samp_acc(Fd, p.x, p.y, q.x, q.y, cd, sd);
  }
  __shared__ float shc[4][4], shs[4][4];
  const int lane = threadIdx.x & 63, wv = threadIdx.x >> 6;
  float c4[4] = {ca, cb, cc, cd};
  float s4[4] = {sa, sb, sc_, sd};
  static_for<4>([&](auto m) {
    float c = c4[m], s = s4[m];
#pragma unroll
    for (int o = 32; o > 0; o >>= 1) {
      c += __shfl_down(c, o);
      s += __shfl_down(s, o);
    }
    if (lane == 0) { shc[wv][m] = c; shs[wv][m] = s; }
  });
  __syncthreads();
  if (threadIdx.x < 4 && m0 + threadIdx.x < iters) {
    const int m = threadIdx.x;
    ml[m0 + m] = shc[0][m] + shc[1][m] + shc[2][m] + shc[3][m];
    ssum[m0 + m] = shs[0][m] + shs[1][m] + shs[2][m] + shs[3][m];
  }
}

// ============================================================
// Kernel 3: select (redundant/block, R10-proven) + mask + mean-sums +
// 36 RAW moments (no means needed!) + ticket barrier + dist-sums.
// No 45-double accumulator anywhere -> no spill surface. 64 blocks at
// (256,1) are all co-resident -> spin barrier safe (R11-verified code).
// acc: [0]=sw [1]=Spx [2]=Spy [3]=Sqx [4]=Sqy [5]=sd1 [6]=sd2
//      [7..42]=R[qk*6+pk] raw moments  [43..46]=means broadcast
// sync2: [0]=ticket [1]=flag
// ============================================================
__global__ __launch_bounds__(256, 1) void selmask_mom(
    const float2* __restrict__ P1, const float2* __restrict__ P2,
    const float* __restrict__ models, const float* __restrict__ ml,
    const float* __restrict__ ssum, const int* __restrict__ uniq,
    float* __restrict__ outmask, double* __restrict__ acc,
    unsigned int* __restrict__ sync2, int N, int iters, int NB) {
  const int tid = threadIdx.x;
  __shared__ float ra[256], rb[256];
  __shared__ int rid[256];
  // ---- phase A: select_best
  float mlmax = 0.f, mnmax = -INFINITY;
  for (int i = tid; i < iters; i += 256) {
    if (uniq[i]) {
      float m = ml[i];
      mlmax = fmaxf(mlmax, m);
      float mean = (ssum[i] + 1e-8f) / (m + 1e-8f);
      mnmax = fmaxf(mnmax, mean);
    }
  }
  ra[tid] = mlmax;
  rb[tid] = mnmax;
  __syncthreads();
  for (int s = 128; s > 0; s >>= 1) {
    if (tid < s) {
      ra[tid] = fmaxf(ra[tid], ra[tid + s]);
      rb[tid] = fmaxf(rb[tid], rb[tid + s]);
    }
    __syncthreads();
  }
  const float MLMAX = ra[0];
  const float MNMAX = rb[0];
  __syncthreads();
  float bsc = -INFINITY;
  int bid = 0x7FFFFFFF;
  for (int i = tid; i < iters; i += 256) {
    float sc = -INFINITY;
    float m = ml[i];
    float mean = (ssum[i] + 1e-8f) / (m + 1e-8f);
    if (uniq[i]) sc = 0.5f * (m / MLMAX) + 0.5f * (1.0f - mean / MNMAX);
    if (sc > bsc || (sc == bsc && i < bid)) { bsc = sc; bid = i; }
  }
  ra[tid] = bsc;
  rid[tid] = bid;
  __syncthreads();
  for (int s = 128; s > 0; s >>= 1) {
    if (tid < s) {
      if (ra[tid + s] > ra[tid] ||
          (ra[tid + s] == ra[tid] && rid[tid + s] < rid[tid])) {
        ra[tid] = ra[tid + s];
        rid[tid] = rid[tid + s];
      }
    }
    __syncthreads();
  }
  const int best = rid[0];

  // ---- phase B: mask + mean-sums + 36 raw moments (inliers only)
  const int i = blockIdx.x * 256 + tid;
  float pxf = 0.f, pyf = 0.f, qxf = 0.f, qyf = 0.f;
  bool in = false;
  if (i < N) {
    const F9 F = loadF(models + (size_t)best * 9);
    const float2 p = P1[i];
    const float2 q = P2[i];
    pxf = p.x; pyf = p.y; qxf = q.x; qyf = q.y;
    float num, den, dd;
    samp_numden(F, pxf, pyf, qxf, qyf, num, den, dd);
    in = (num <= den);  // same predicate as sampson_stats4
    outmask[i] = in ? 1.0f : 0.0f;
  }
  const int lane = tid & 63;
  const double px = (double)pxf, py = (double)pyf;
  const double qx = (double)qxf, qy = (double)qyf;
  {
    double w = in ? 1.0 : 0.0;
    double a = in ? px : 0.0, b = in ? py : 0.0;
    double c = in ? qx : 0.0, d = in ? qy : 0.0;
#pragma unroll
    for (int o = 32; o > 0; o >>= 1) {
      w += __shfl_down(w, o); a += __shfl_down(a, o); b += __shfl_down(b, o);
      c += __shfl_down(c, o); d += __shfl_down(d, o);
    }
    if (lane == 0) {
      atomicAdd(&acc[0], w); atomicAdd(&acc[1], a); atomicAdd(&acc[2], b);
      atomicAdd(&acc[3], c); atomicAdd(&acc[4], d);
    }
  }
  // monomials (6 per side); moments reduced one at a time (low live count)
  {
    double um0 = 1.0, um1 = qx, um2 = qy, um3 = qx * qx, um4 = qx * qy,
           um5 = qy * qy;
    double vm0 = 1.0, vm1 = px, vm2 = py, vm3 = px * px, vm4 = px * py,
           vm5 = py * py;
    const double uu[6] = {um0, um1, um2, um3, um4, um5};
    const double vv[6] = {vm0, vm1, vm2, vm3, vm4, vm5};
    static_for<6>([&](auto QK) {
      static_for<6>([&](auto PK) {
        double prod = in ? uu[QK] * vv[PK] : 0.0;
#pragma unroll
        for (int o = 32; o > 0; o >>= 1) prod += __shfl_down(prod, o);
        if (lane == 0)
          atomicAdd(&acc[7 + decltype(QK)::value * 6 + decltype(PK)::value],
                    prod);
      });
    });
  }

  // ---- ticket barrier (R11-verified): last block publishes means
  __syncthreads();
  __shared__ int amLast;
  if (tid == 0) {
    __threadfence();
    amLast = (atomicAdd(&sync2[0], 1u) == (unsigned int)(NB - 1)) ? 1 : 0;
  }
  __syncthreads();
  if (amLast && tid == 0) {
    const double WS = atomicAdd(&acc[0], 0.0);
    acc[43] = atomicAdd(&acc[1], 0.0) / WS;  // M1X (p-side)
    acc[44] = atomicAdd(&acc[2], 0.0) / WS;  // M1Y
    acc[45] = atomicAdd(&acc[3], 0.0) / WS;  // M2X (q-side)
    acc[46] = atomicAdd(&acc[4], 0.0) / WS;  // M2Y
    __threadfence();
    atomicExch(&sync2[1], 1u);
  }
  __shared__ double smean[4];
  if (tid == 0) {
    while (atomicAdd(&sync2[1], 0u) == 0u) {
      __builtin_amdgcn_s_sleep(1);
    }
    __threadfence();
    smean[0] = atomicAdd(&acc[43], 0.0);
    smean[1] = atomicAdd(&acc[44], 0.0);
    smean[2] = atomicAdd(&acc[45], 0.0);
    smean[3] = atomicAdd(&acc[46], 0.0);
  }
  __syncthreads();
  const double M1X = smean[0], M1Y = smean[1];
  const double M2X = smean[2], M2Y = smean[3];

  // ---- phase C: dist sums (point + flag still in registers)
  double sd1 = 0, sd2 = 0;
  if (in) {
    const double v0 = px - M1X, v1 = py - M1Y;
    const double u0 = qx - M2X, u1 = qy - M2Y;
    sd1 = sqrt(v0 * v0 + v1 * v1);
    sd2 = sqrt(u0 * u0 + u1 * u1);
  }
#pragma unroll
  for (int o = 32; o > 0; o >>= 1) {
    sd1 += __shfl_down(sd1, o);
    sd2 += __shfl_down(sd2, o);
  }
  if (lane == 0) {
    atomicAdd(&acc[5], sd1);
    atomicAdd(&acc[6], sd2);
  }
}

// ============================================================
// Kernel 4: solve (dedicated kernel -> registerizes; R7/R10 evidence).
// Builds centered 4th-order moments C from raw R + means (binomial
// expansion), maps to the 45 packed AtA entries via the Kronecker
// structure AtA = sum(uu^T (x) vv^T), applies D*M*D, then solves.
// ============================================================
__global__ __launch_bounds__(64, 1) void ff_solve(const double* __restrict__ acc,
                                                  float* __restrict__ outF) {
  if (threadIdx.x != 0 || blockIdx.x != 0) return;
  const double WS = acc[0];
  const double M1X = acc[1] / WS, M1Y = acc[2] / WS;
  const double M2X = acc[3] / WS, M2Y = acc[4] / WS;
  const double S1 = sqrt(2.0) / (acc[5] / WS + 1e-8);
  const double S2 = sqrt(2.0) / (acc[6] / WS + 1e-8);
  double R[36];
  static_for<36>([&](auto r) { R[r] = acc[7 + r]; });
  // centered mixed moments: C(g1,g2,h1,h2) = sum (qx-M2X)^g1 (qy-M2Y)^g2
  //                                              (px-M1X)^h1 (py-M1Y)^h2
  double C[36];
  static_for<6>([&](auto QP) {
    static_for<6>([&](auto PP) {
      constexpr int qp = decltype(QP)::value;
      constexpr int pp = decltype(PP)::value;
      constexpr int g1 = E1(qp), g2 = E2(qp), h1 = E1(pp), h2 = E2(pp);
      double s = 0.0;
      static_for<g1 + 1>([&](auto I_) {
        static_for<g2 + 1>([&](auto J_) {
          static_for<h1 + 1>([&](auto K_) {
            static_for<h2 + 1>([&](auto L_) {
              constexpr int ii = decltype(I_)::value;
              constexpr int jj = decltype(J_)::value;
              constexpr int kk = decltype(K_)::value;
              constexpr int ll = decltype(L_)::value;
              constexpr double bc =
                  BIN(g1, ii) * BIN(g2, jj) * BIN(h1, kk) * BIN(h2, ll);
              s += bc * ipw<g1 - ii>(-M2X) * ipw<g2 - jj>(-M2Y) *
                   ipw<h1 - kk>(-M1X) * ipw<h2 - ll>(-M1Y) *
                   R[EIDX(ii, jj) * 6 + EIDX(kk, ll)];
            });
          });
        });
      });
      C[qp * 6 + pp] = s;
    });
  });
  // map to packed AtA: entry (i=3r+c, j=3r'+c') = C[qpair(r,r'), ppair(c,c')]
  double M[45];
  static_for<9>([&](auto I_) {
    static_for<9>([&](auto J_) {
      constexpr int i = decltype(I_)::value;
      constexpr int j = decltype(J_)::value;
      if constexpr (j <= i) {
        constexpr int r = i / 3, c = i % 3, r2 = j / 3, c2 = j % 3;
        constexpr int g1 = (r == 0) + (r2 == 0), g2 = (r == 1) + (r2 == 1);
        constexpr int h1 = (c == 0) + (c2 == 0), h2 = (c == 1) + (c2 == 1);
        M[PIX(i, j)] = C[EIDX(g1, g2) * 6 + EIDX(h1, h2)];
      }
    });
  });
  // apply D * M * D, D_(3r+c) = S2^[r<2] * S1^[c<2]
  static_for<9>([&](auto I_) {
    static_for<9>([&](auto J_) {
      constexpr int i = decltype(I_)::value;
      constexpr int j = decltype(J_)::value;
      if constexpr (j <= i) {
        const double sr = ((i / 3) < 2 ? S2 : 1.0) * ((i % 3) < 2 ? S1 : 1.0);
        const double sc = ((j / 3) < 2 ? S2 : 1.0) * ((j % 3) < 2 ? S1 : 1.0);
        M[PIX(i, j)] *= sr * sc;
      }
    });
  });
  solveF(M, S1, M1X, M1Y, S2, M2X, M2Y, outF);
}

// ============================================================
// Host launcher — 4 dispatches
// ============================================================
extern "C" void kernel_launch(void* const* d_in, const int* in_sizes, int n_in,
                              void* d_out, int out_size, void* d_ws, size_t ws_size,
                              hipStream_t stream) {
  const float* pts1 = (const float*)d_in[0];
  const float* pts2 = (const float*)d_in[1];
  const int* samples = (const int*)d_in[2];
  const int N = in_sizes[0] / 3;      // 16384
  const int iters = in_sizes[2] / 8;  // 4096

  // workspace layout (16B-aligned start)
  float2* P1 = (float2*)d_ws;                        // N float2
  float2* P2 = P1 + N;                               // N float2
  double* acc = (double*)(P2 + N);                   // 48 doubles
  unsigned int* sync2 = (unsigned int*)(acc + 48);   // ticket, flag (+pad)
  float* models = (float*)(sync2 + 4);               // iters*9
  float* ml = models + (size_t)iters * 9;            // iters
  float* ssum = ml + iters;                          // iters
  int* uniq = (int*)(ssum + iters);                  // iters

  float* outF = (float*)d_out;  // 9 floats (Mbest)
  float* outmask = outF + 9;    // N floats (0/1)

  const int TB = (N + 255) / 256;
  const int FB = (iters + 63) / 64;
  const int NB = (N + 255) / 256;  // 64 blocks, co-resident at (256,1)
  prep_and_fit<<<TB + FB, 256, 0, stream>>>(pts1, pts2, samples, P1, P2,
                                            models, uniq, acc, sync2, N,
                                            iters, TB);
  sampson_stats4<<<(iters + 3) / 4, 256, 0, stream>>>(P1, P2, models, ml, ssum,
                                                      N, iters);
  selmask_mom<<<NB, 256, 0, stream>>>(P1, P2, models, ml, ssum, uniq, outmask,
                                      acc, sync2, N, iters, NB);
  ff_solve<<<1, 64, 0, stream>>>(acc, outF);
}

// Round 16
// 182.822 us; speedup vs baseline: 1.2045x; 1.2045x over previous
//
#include <hip/hip_runtime.h>
#include <math.h>
#include <type_traits>
#include <utility>

#if defined(__has_builtin)
#if __has_builtin(__builtin_amdgcn_rcpf)
#define FAST_RCPF(x) __builtin_amdgcn_rcpf(x)
#endif
#if __has_builtin(__builtin_amdgcn_rsqf)
#define FAST_RSQF(x) __builtin_amdgcn_rsqf(x)
#endif
#endif
#ifndef FAST_RCPF
#define FAST_RCPF(x) (1.0f / (x))
#endif
#ifndef FAST_RSQF
#define FAST_RSQF(x) (1.0f / sqrtf(x))
#endif

// packed lower-tri index (constexpr -> folds in templates)
__host__ __device__ constexpr int PIX(int i, int j) { return i * (i + 1) / 2 + j; }

// ============================================================
// RULES (hard-won):
//  R6/R7: SROA runs before unrolling, never re-runs -> template-constant
//         indices only for per-thread arrays.
//  R9/R11: a kernel holding a 45-double per-thread accumulator must be
//         dedicated+simple. (R16: streaming path has NO such accumulator --
//         one point per thread, entries computed on the fly.)
//  R13:  no mixed packed/scalar f32 dataflow (LDS spill).
//  R14:  sampson: 4 models/block is the sweet spot; not occupancy-bound.
//  R15:  global f64 atomics from many waves to few addresses serialize at
//        ~0.4us each; soft grid barriers cost >> a 20us dispatch boundary.
//        -> this version: zero global atomics, zero barriers; per-block
//        partials + redundant mean computation (1% extra VALU).
// ============================================================
template <int N, int I = 0, typename F>
__device__ __forceinline__ void static_for(F&& f) {
  if constexpr (I < N) {
    f(std::integral_constant<int, I>{});
    static_for<N, I + 1>(static_cast<F&&>(f));
  }
}

// ---------- 9x9 packed Cholesky, template-indexed ----------
template <int I, int J, int K>
__device__ __forceinline__ double csub9(const double* M, double s) {
  if constexpr (K >= J) return s;
  else return csub9<I, J, K + 1>(M, s - M[PIX(I, K)] * M[PIX(J, K)]);
}
template <int I, int J>
__device__ __forceinline__ void cholJ(double* M) {
  if constexpr (J <= I) {
    double s = csub9<I, J, 0>(M, M[PIX(I, J)]);
    if constexpr (J == I)
      M[PIX(I, I)] = sqrt(fmax(s, 1e-300));
    else
      M[PIX(I, J)] = s / M[PIX(J, J)];
    cholJ<I, J + 1>(M);
  }
}
template <int I>
__device__ __forceinline__ void cholI(double* M) {
  if constexpr (I < 9) {
    cholJ<I, 0>(M);
    cholI<I + 1>(M);
  }
}

// ---------- forward/backward substitution, template-indexed ----------
template <int I, int K>
__device__ __forceinline__ double fsub9(const double* L, const double* x, double s) {
  if constexpr (K >= I) return s;
  else return fsub9<I, K + 1>(L, x, s - L[PIX(I, K)] * x[K]);
}
template <int I>
__device__ __forceinline__ void fwd9(const double* L, double* x) {
  if constexpr (I < 9) {
    x[I] = fsub9<I, 0>(L, x, x[I]) / L[PIX(I, I)];
    fwd9<I + 1>(L, x);
  }
}
template <int I, int K>
__device__ __forceinline__ double bsub9(const double* L, const double* x, double s) {
  if constexpr (K >= 9) return s;
  else return bsub9<I, K + 1>(L, x, s - L[PIX(K, I)] * x[K]);
}
template <int I>
__device__ __forceinline__ void bwd9(const double* L, double* x) {
  if constexpr (I >= 0) {
    x[I] = bsub9<I, I + 1>(L, x, x[I]) / L[PIX(I, I)];
    bwd9<I - 1>(L, x);
  }
}

// ---------- AtA rank-1 update (fit kernel only) ----------
template <int I, int J>
__device__ __forceinline__ void ataIJ(double* M, const double (&a)[9], double w) {
  if constexpr (J <= I) {
    M[PIX(I, J)] += w * a[I] * a[J];
    ataIJ<I, J + 1>(M, a, w);
  }
}
template <int I>
__device__ __forceinline__ void ataI(double* M, const double (&a)[9], double w) {
  if constexpr (I < 9) {
    ataIJ<I, 0>(M, a, w);
    ataI<I + 1>(M, a, w);
  }
}

// ---------- 3x3 Jacobi rotation on named scalars ----------
#define JROT(P, Q)                                                              \
  {                                                                             \
    double apq = a##P##Q;                                                       \
    if (fabs(apq) >= 1e-300) {                                                  \
      double tau = (a##Q##Q - a##P##P) / (2.0 * apq);                           \
      double t = ((tau >= 0.0) ? 1.0 : -1.0) / (fabs(tau) + sqrt(1.0 + tau * tau)); \
      double c = 1.0 / sqrt(1.0 + t * t);                                       \
      double s = t * c;                                                         \
      double t0p = a0##P, t0q = a0##Q;                                          \
      a0##P = c * t0p - s * t0q; a0##Q = s * t0p + c * t0q;                     \
      double t1p = a1##P, t1q = a1##Q;                                          \
      a1##P = c * t1p - s * t1q; a1##Q = s * t1p + c * t1q;                     \
      double t2p = a2##P, t2q = a2##Q;                                          \
      a2##P = c * t2p - s * t2q; a2##Q = s * t2p + c * t2q;                     \
      double rp0 = a##P##0, rq0 = a##Q##0;                                      \
      a##P##0 = c * rp0 - s * rq0; a##Q##0 = s * rp0 + c * rq0;                 \
      double rp1 = a##P##1, rq1 = a##Q##1;                                      \
      a##P##1 = c * rp1 - s * rq1; a##Q##1 = s * rp1 + c * rq1;                 \
      double rp2 = a##P##2, rq2 = a##Q##2;                                      \
      a##P##2 = c * rp2 - s * rq2; a##Q##2 = s * rp2 + c * rq2;                 \
      double u0p = V0##P, u0q = V0##Q;                                          \
      V0##P = c * u0p - s * u0q; V0##Q = s * u0p + c * u0q;                     \
      double u1p = V1##P, u1q = V1##Q;                                          \
      V1##P = c * u1p - s * u1q; V1##Q = s * u1p + c * u1q;                     \
      double u2p = V2##P, u2q = V2##Q;                                          \
      V2##P = c * u2p - s * u2q; V2##Q = s * u2p + c * u2q;                     \
    }                                                                           \
  }

// ---------- full solver: null vec of AtA -> rank-2 -> denormalize ----------
__device__ __forceinline__ void solveF(double* M, double s1, double m1x, double m1y,
                                       double s2, double m2x, double m2y,
                                       float* out) {
  double tr = M[0] + M[2] + M[5] + M[9] + M[14] + M[20] + M[27] + M[35] + M[44];
  double shift = 1e-12 * tr;
  M[0] += shift; M[2] += shift; M[5] += shift; M[9] += shift; M[14] += shift;
  M[20] += shift; M[27] += shift; M[35] += shift; M[44] += shift;
  cholI<0>(M);
  double x[9];
  static_for<9>([&](auto i) { x[i] = 1.0; });
  static_for<3>([&](auto) {
    fwd9<0>(M, x);
    bwd9<8>(M, x);
    double n = 0.0;
    static_for<9>([&](auto i) { n += x[i] * x[i]; });
    n = 1.0 / sqrt(n);
    static_for<9>([&](auto i) { x[i] *= n; });
  });
  const double g00 = x[0] * x[0] + x[3] * x[3] + x[6] * x[6];
  const double g01 = x[0] * x[1] + x[3] * x[4] + x[6] * x[7];
  const double g02 = x[0] * x[2] + x[3] * x[5] + x[6] * x[8];
  const double g11 = x[1] * x[1] + x[4] * x[4] + x[7] * x[7];
  const double g12 = x[1] * x[2] + x[4] * x[5] + x[7] * x[8];
  const double g22 = x[2] * x[2] + x[5] * x[5] + x[8] * x[8];
  double a00 = g00, a01 = g01, a02 = g02;
  double a10 = g01, a11 = g11, a12 = g12;
  double a20 = g02, a21 = g12, a22 = g22;
  double V00 = 1, V01 = 0, V02 = 0;
  double V10 = 0, V11 = 1, V12 = 0;
  double V20 = 0, V21 = 0, V22 = 1;
  for (int sweep = 0; sweep < 6; ++sweep) {
    JROT(0, 1);
    JROT(0, 2);
    JROT(1, 2);
  }
  double mv = a00, v0 = V00, v1 = V10, v2 = V20;
  if (a11 < mv) { mv = a11; v0 = V01; v1 = V11; v2 = V21; }
  if (a22 < mv) { mv = a22; v0 = V02; v1 = V12; v2 = V22; }
  const double fv0 = x[0] * v0 + x[1] * v1 + x[2] * v2;
  const double fv1 = x[3] * v0 + x[4] * v1 + x[5] * v2;
  const double fv2 = x[6] * v0 + x[7] * v1 + x[8] * v2;
  const double F200 = x[0] - fv0 * v0, F201 = x[1] - fv0 * v1, F202 = x[2] - fv0 * v2;
  const double F210 = x[3] - fv1 * v0, F211 = x[4] - fv1 * v1, F212 = x[5] - fv1 * v2;
  const double F220 = x[6] - fv2 * v0, F221 = x[7] - fv2 * v1, F222 = x[8] - fv2 * v2;
  const double R00 = s2 * F200, R01 = s2 * F201, R02 = s2 * F202;
  const double R10 = s2 * F210, R11 = s2 * F211, R12 = s2 * F212;
  const double R20 = -s2 * m2x * F200 - s2 * m2y * F210 + F220;
  const double R21 = -s2 * m2x * F201 - s2 * m2y * F211 + F221;
  const double R22 = -s2 * m2x * F202 - s2 * m2y * F212 + F222;
  const double Ff00 = s1 * R00, Ff01 = s1 * R01;
  const double Ff02 = -s1 * m1x * R00 - s1 * m1y * R01 + R02;
  const double Ff10 = s1 * R10, Ff11 = s1 * R11;
  const double Ff12 = -s1 * m1x * R10 - s1 * m1y * R11 + R12;
  const double Ff20 = s1 * R20, Ff21 = s1 * R21;
  const double Ff22 = -s1 * m1x * R20 - s1 * m1y * R21 + R22;
  const double inv = 1.0 / Ff22;
  out[0] = (float)(Ff00 * inv); out[1] = (float)(Ff01 * inv); out[2] = (float)(Ff02 * inv);
  out[3] = (float)(Ff10 * inv); out[4] = (float)(Ff11 * inv); out[5] = (float)(Ff12 * inv);
  out[6] = (float)(Ff20 * inv); out[7] = (float)(Ff21 * inv); out[8] = (float)(Ff22 * inv);
}

// ============================================================
// Sampson terms (z==1.0 exactly; elision is bit-identical)
// ============================================================
struct F9 {
  float f0, f1, f2, f3, f4, f5, f6, f7, f8;
};

__device__ __forceinline__ F9 loadF(const float* __restrict__ p) {
  F9 F;
  F.f0 = p[0]; F.f1 = p[1]; F.f2 = p[2];
  F.f3 = p[3]; F.f4 = p[4]; F.f5 = p[5];
  F.f6 = p[6]; F.f7 = p[7]; F.f8 = p[8];
  return F;
}

__device__ __forceinline__ void samp_numden(const F9& F, float px, float py,
                                            float qx, float qy, float& num,
                                            float& den, float& dout) {
  float a0 = fmaf(F.f0, px, fmaf(F.f1, py, F.f2));
  float a1 = fmaf(F.f3, px, fmaf(F.f4, py, F.f5));
  float a2 = fmaf(F.f6, px, fmaf(F.f7, py, F.f8));
  float b0 = fmaf(F.f0, qx, fmaf(F.f3, qy, F.f6));
  float b1 = fmaf(F.f1, qx, fmaf(F.f4, qy, F.f7));
  float d = fmaf(qx, a0, fmaf(qy, a1, a2));
  num = d * d;
  den = fmaf(a0, a0, fmaf(a1, a1, fmaf(b0, b0, b1 * b1)));
  dout = d;
}

// predicate num<=den is EXACT (same every round); sqrt(err) = |d|*rsqrt(den).
__device__ __forceinline__ void samp_acc(const F9& F, float px, float py,
                                         float qx, float qy, float& cnt,
                                         float& ss) {
  float num, den, d;
  samp_numden(F, px, py, qx, qy, num, den, d);
  const bool in = (num <= den);
  const float val = fabsf(d) * FAST_RSQF(den);
  cnt += in ? 1.0f : 0.0f;
  ss += in ? val : 0.0f;
}

// ============================================================
// Kernel 1: transpose blocks [0,TB) (float2 x,y) + fit blocks [TB,..)
// ============================================================
__global__ __launch_bounds__(256, 1) void prep_and_fit(
    const float* __restrict__ pts1, const float* __restrict__ pts2,
    const int* __restrict__ samples, float2* __restrict__ P1,
    float2* __restrict__ P2, float* __restrict__ models,
    int* __restrict__ uflag, int N, int iters, int TB) {
  if ((int)blockIdx.x < TB) {
    const int i = blockIdx.x * 256 + threadIdx.x;
    if (i < N) {
      P1[i] = make_float2(pts1[3 * i], pts1[3 * i + 1]);
      P2[i] = make_float2(pts2[3 * i], pts2[3 * i + 1]);
    }
    return;
  }
  if (threadIdx.x >= 64) return;
  const int it = (blockIdx.x - TB) * 64 + threadIdx.x;
  if (it >= iters) return;

  int idx[8];
  static_for<8>([&](auto k) { idx[k] = samples[it * 8 + k]; });
  int u = 1;
  static_for<8>([&](auto A) {
    static_for<8>([&](auto B) {
      if constexpr (decltype(B)::value > decltype(A)::value) {
        if (idx[A] == idx[B]) u = 0;
      }
    });
  });
  uflag[it] = u;

  float X1[8], Y1[8], Z1[8], X2[8], Y2[8], Z2[8];
  static_for<8>([&](auto k) {
    const int j = idx[k];
    X1[k] = pts1[3 * j]; Y1[k] = pts1[3 * j + 1]; Z1[k] = pts1[3 * j + 2];
    X2[k] = pts2[3 * j]; Y2[k] = pts2[3 * j + 1]; Z2[k] = pts2[3 * j + 2];
  });
  double sx1 = 0, sy1 = 0, sx2 = 0, sy2 = 0;
  static_for<8>([&](auto k) {
    sx1 += (double)X1[k]; sy1 += (double)Y1[k];
    sx2 += (double)X2[k]; sy2 += (double)Y2[k];
  });
  const double m1x = sx1 / 8.0, m1y = sy1 / 8.0;
  const double m2x = sx2 / 8.0, m2y = sy2 / 8.0;
  double sd1 = 0, sd2 = 0;
  static_for<8>([&](auto k) {
    double dx1 = (double)X1[k] - m1x, dy1 = (double)Y1[k] - m1y;
    double dx2 = (double)X2[k] - m2x, dy2 = (double)Y2[k] - m2y;
    sd1 += sqrt(dx1 * dx1 + dy1 * dy1);
    sd2 += sqrt(dx2 * dx2 + dy2 * dy2);
  });
  const double s1 = sqrt(2.0) / (sd1 / 8.0 + 1e-8);
  const double s2 = sqrt(2.0) / (sd2 / 8.0 + 1e-8);

  double M[45];
  static_for<45>([&](auto r) { M[r] = 0.0; });
  static_for<8>([&](auto k) {
    const double z1 = (double)Z1[k], z2 = (double)Z2[k];
    const double p1x = s1 * ((double)X1[k] - m1x * z1);
    const double p1y = s1 * ((double)Y1[k] - m1y * z1);
    const double p2x = s2 * ((double)X2[k] - m2x * z2);
    const double p2y = s2 * ((double)Y2[k] - m2y * z2);
    const double a[9] = {p2x * p1x, p2x * p1y, p2x * z1,
                         p2y * p1x, p2y * p1y, p2y * z1,
                         z2 * p1x,  z2 * p1y,  z2 * z1};
    ataI<0>(M, a, 1.0);
  });
  solveF(M, s1, m1x, m1y, s2, m2x, m2y, models + (size_t)it * 9);
}

// ============================================================
// Kernel 2: 4 models/block (R12-proven: 43.4us), float2 loads
// ============================================================
__global__ __launch_bounds__(256, 4) void sampson_stats4(
    const float2* __restrict__ P1, const float2* __restrict__ P2,
    const float* __restrict__ models, float* __restrict__ ml,
    float* __restrict__ ssum, int N, int iters) {
  const int m0 = blockIdx.x * 4;
  const int c0 = min(m0 + 0, iters - 1), c1 = min(m0 + 1, iters - 1);
  const int c2 = min(m0 + 2, iters - 1), c3 = min(m0 + 3, iters - 1);
  const F9 Fa = loadF(models + (size_t)c0 * 9);
  const F9 Fb = loadF(models + (size_t)c1 * 9);
  const F9 Fc = loadF(models + (size_t)c2 * 9);
  const F9 Fd = loadF(models + (size_t)c3 * 9);
  float ca = 0, cb = 0, cc = 0, cd = 0;
  float sa = 0, sb = 0, sc_ = 0, sd = 0;
  const int NP = N & ~511;
  for (int i = threadIdx.x; i < NP; i += 512) {
    const float2 pA = P1[i];
    const float2 qA = P2[i];
    const float2 pB = P1[i + 256];
    const float2 qB = P2[i + 256];
    samp_acc(Fa, pA.x, pA.y, qA.x, qA.y, ca, sa);
    samp_acc(Fb, pA.x, pA.y, qA.x, qA.y, cb, sb);
    samp_acc(Fc, pA.x, pA.y, qA.x, qA.y, cc, sc_);
    samp_acc(Fd, pA.x, pA.y, qA.x, qA.y, cd, sd);
    samp_acc(Fa, pB.x, pB.y, qB.x, qB.y, ca, sa);
    samp_acc(Fb, pB.x, pB.y, qB.x, qB.y, cb, sb);
    samp_acc(Fc, pB.x, pB.y, qB.x, qB.y, cc, sc_);
    samp_acc(Fd, pB.x, pB.y, qB.x, qB.y, cd, sd);
  }
  for (int i = NP + threadIdx.x; i < N; i += 256) {
    const float2 p = P1[i];
    const float2 q = P2[i];
    samp_acc(Fa, p.x, p.y, q.x, q.y, ca, sa);
    samp_acc(Fb, p.x, p.y, q.x, q.y, cb, sb);
    samp_acc(Fc, p.x, p.y, q.x, q.y, cc, sc_);
    samp_acc(Fd, p.x, p.y, q.x, q.y, cd, sd);
  }
  __shared__ float shc[4][4], shs[4][4];
  const int lane = threadIdx.x & 63, wv = threadIdx.x >> 6;
  float c4[4] = {ca, cb, cc, cd};
  float s4[4] = {sa, sb, sc_, sd};
  static_for<4>([&](auto m) {
    float c = c4[m], s = s4[m];
#pragma unroll
    for (int o = 32; o > 0; o >>= 1) {
      c += __shfl_down(c, o);
      s += __shfl_down(s, o);
    }
    if (lane == 0) { shc[wv][m] = c; shs[wv][m] = s; }
  });
  __syncthreads();
  if (threadIdx.x < 4 && m0 + threadIdx.x < iters) {
    const int m = threadIdx.x;
    ml[m0 + m] = shc[0][m] + shc[1][m] + shc[2][m] + shc[3][m];
    ssum[m0 + m] = shs[0][m] + shs[1][m] + shs[2][m] + shs[3][m];
  }
}

// ============================================================
// Kernel 3: select (redundant/block) + REDUNDANT full-N means (replaces
// the grid barrier: ~1% extra VALU, bitwise-identical across blocks) +
// own-slice mask + centered AtA partials. ZERO global atomics.
// partials[b*48 + k]: k=0..44 AtA, 45=sd1, 46=sd2 (plain stores).
// Block 0 additionally stores means to meanout[0..4].
// ============================================================
__global__ __launch_bounds__(256) void selmask_part(
    const float2* __restrict__ P1, const float2* __restrict__ P2,
    const float* __restrict__ models, const float* __restrict__ ml,
    const float* __restrict__ ssum, const int* __restrict__ uniq,
    float* __restrict__ outmask, double* __restrict__ partials,
    double* __restrict__ meanout, int N, int iters) {
  const int tid = threadIdx.x;
  const int lane = tid & 63, wv = tid >> 6;
  __shared__ float ra[256], rb[256];
  __shared__ int rid[256];
  // ---- phase A: select_best (identical math every round)
  float mlmax = 0.f, mnmax = -INFINITY;
  for (int i = tid; i < iters; i += 256) {
    if (uniq[i]) {
      float m = ml[i];
      mlmax = fmaxf(mlmax, m);
      float mean = (ssum[i] + 1e-8f) / (m + 1e-8f);
      mnmax = fmaxf(mnmax, mean);
    }
  }
  ra[tid] = mlmax;
  rb[tid] = mnmax;
  __syncthreads();
  for (int s = 128; s > 0; s >>= 1) {
    if (tid < s) {
      ra[tid] = fmaxf(ra[tid], ra[tid + s]);
      rb[tid] = fmaxf(rb[tid], rb[tid + s]);
    }
    __syncthreads();
  }
  const float MLMAX = ra[0];
  const float MNMAX = rb[0];
  __syncthreads();
  float bsc = -INFINITY;
  int bid = 0x7FFFFFFF;
  for (int i = tid; i < iters; i += 256) {
    float sc = -INFINITY;
    float m = ml[i];
    float mean = (ssum[i] + 1e-8f) / (m + 1e-8f);
    if (uniq[i]) sc = 0.5f * (m / MLMAX) + 0.5f * (1.0f - mean / MNMAX);
    if (sc > bsc || (sc == bsc && i < bid)) { bsc = sc; bid = i; }
  }
  ra[tid] = bsc;
  rid[tid] = bid;
  __syncthreads();
  for (int s = 128; s > 0; s >>= 1) {
    if (tid < s) {
      if (ra[tid + s] > ra[tid] ||
          (ra[tid + s] == ra[tid] && rid[tid + s] < rid[tid])) {
        ra[tid] = ra[tid + s];
        rid[tid] = rid[tid + s];
      }
    }
    __syncthreads();
  }
  const int best = rid[0];
  const F9 F = loadF(models + (size_t)best * 9);

  // ---- phase B: REDUNDANT full-N mean sums (same loop order in every
  // block -> bitwise-identical means; no cross-block communication)
  __shared__ double sm[5][4];
  double sw = 0, spx = 0, spy = 0, sqx = 0, sqy = 0;
  for (int i = tid; i < N; i += 256) {
    const float2 p = P1[i];
    const float2 q = P2[i];
    float num, den, dd;
    samp_numden(F, p.x, p.y, q.x, q.y, num, den, dd);
    if (num <= den) {
      sw += 1.0;
      spx += (double)p.x;
      spy += (double)p.y;
      sqx += (double)q.x;
      sqy += (double)q.y;
    }
  }
  {
    double v0 = sw, v1 = spx, v2 = spy, v3 = sqx, v4 = sqy;
#pragma unroll
    for (int o = 32; o > 0; o >>= 1) {
      v0 += __shfl_down(v0, o); v1 += __shfl_down(v1, o);
      v2 += __shfl_down(v2, o); v3 += __shfl_down(v3, o);
      v4 += __shfl_down(v4, o);
    }
    if (lane == 0) {
      sm[0][wv] = v0; sm[1][wv] = v1; sm[2][wv] = v2;
      sm[3][wv] = v3; sm[4][wv] = v4;
    }
  }
  __syncthreads();
  const double WS = sm[0][0] + sm[0][1] + sm[0][2] + sm[0][3];
  const double M1X = (sm[1][0] + sm[1][1] + sm[1][2] + sm[1][3]) / WS;
  const double M1Y = (sm[2][0] + sm[2][1] + sm[2][2] + sm[2][3]) / WS;
  const double M2X = (sm[3][0] + sm[3][1] + sm[3][2] + sm[3][3]) / WS;
  const double M2Y = (sm[4][0] + sm[4][1] + sm[4][2] + sm[4][3]) / WS;
  if (blockIdx.x == 0 && tid == 0) {
    meanout[0] = WS;
    meanout[1] = M1X; meanout[2] = M1Y;
    meanout[3] = M2X; meanout[4] = M2Y;
  }
  __syncthreads();

  // ---- phase C: own point -> mask + centered terms; block-reduce 47
  // values into partials (plain stores, no atomics).
  const int i = blockIdx.x * 256 + tid;
  double u0 = 0, u1 = 0, v0 = 0, v1 = 0, a8 = 0, sd1 = 0, sd2 = 0;
  if (i < N) {
    const float2 p = P1[i];
    const float2 q = P2[i];
    float num, den, dd;
    samp_numden(F, p.x, p.y, q.x, q.y, num, den, dd);
    const bool in = (num <= den);  // same predicate as sampson_stats4
    outmask[i] = in ? 1.0f : 0.0f;
    if (in) {
      v0 = (double)p.x - M1X; v1 = (double)p.y - M1Y;
      u0 = (double)q.x - M2X; u1 = (double)q.y - M2Y;
      a8 = 1.0;
      sd1 = sqrt(v0 * v0 + v1 * v1);
      sd2 = sqrt(u0 * u0 + u1 * u1);
    }
  }
  const double a[9] = {u0 * v0, u0 * v1, u0, u1 * v0, u1 * v1, u1, v0, v1, a8};
  __shared__ double red[47][4];
  static_for<9>([&](auto I_) {
    static_for<9>([&](auto J_) {
      constexpr int ii = decltype(I_)::value;
      constexpr int jj = decltype(J_)::value;
      if constexpr (jj <= ii) {
        double v = a[ii] * a[jj];
#pragma unroll
        for (int o = 32; o > 0; o >>= 1) v += __shfl_down(v, o);
        if (lane == 0) red[PIX(ii, jj)][wv] = v;
      }
    });
  });
  {
    double t1 = sd1, t2 = sd2;
#pragma unroll
    for (int o = 32; o > 0; o >>= 1) {
      t1 += __shfl_down(t1, o);
      t2 += __shfl_down(t2, o);
    }
    if (lane == 0) { red[45][wv] = t1; red[46][wv] = t2; }
  }
  __syncthreads();
  if (tid < 47) {
    partials[(size_t)blockIdx.x * 48 + tid] =
        red[tid][0] + red[tid][1] + red[tid][2] + red[tid][3];
  }
}

// ============================================================
// Kernel 4: reduce partials (47 threads x NB plain reads, deterministic
// order) then thread 0 applies D*M*D + solver (dedicated -> registerizes).
// ============================================================
__global__ __launch_bounds__(64, 1) void ff_solve(
    const double* __restrict__ partials, const double* __restrict__ meanout,
    float* __restrict__ outF, int NB) {
  if (blockIdx.x != 0) return;
  __shared__ double red[47];
  if (threadIdx.x < 47) {
    double s = 0.0;
    for (int b = 0; b < NB; ++b) s += partials[(size_t)b * 48 + threadIdx.x];
    red[threadIdx.x] = s;
  }
  __syncthreads();
  if (threadIdx.x != 0) return;
  const double WS = meanout[0];
  const double M1X = meanout[1], M1Y = meanout[2];
  const double M2X = meanout[3], M2Y = meanout[4];
  const double S1 = sqrt(2.0) / (red[45] / WS + 1e-8);
  const double S2 = sqrt(2.0) / (red[46] / WS + 1e-8);
  double M[45];
  static_for<45>([&](auto r) { M[r] = red[r]; });
  // apply D * M * D, D_(3r+c) = S2^[r<2] * S1^[c<2]
  static_for<9>([&](auto I_) {
    static_for<9>([&](auto J_) {
      constexpr int i = decltype(I_)::value;
      constexpr int j = decltype(J_)::value;
      if constexpr (j <= i) {
        const double sr = ((i / 3) < 2 ? S2 : 1.0) * ((i % 3) < 2 ? S1 : 1.0);
        const double sc = ((j / 3) < 2 ? S2 : 1.0) * ((j % 3) < 2 ? S1 : 1.0);
        M[PIX(i, j)] *= sr * sc;
      }
    });
  });
  solveF(M, S1, M1X, M1Y, S2, M2X, M2Y, outF);
}

// ============================================================
// Host launcher — 4 dispatches, zero atomics, zero barriers
// ============================================================
extern "C" void kernel_launch(void* const* d_in, const int* in_sizes, int n_in,
                              void* d_out, int out_size, void* d_ws, size_t ws_size,
                              hipStream_t stream) {
  const float* pts1 = (const float*)d_in[0];
  const float* pts2 = (const float*)d_in[1];
  const int* samples = (const int*)d_in[2];
  const int N = in_sizes[0] / 3;      // 16384
  const int iters = in_sizes[2] / 8;  // 4096

  const int TB = (N + 255) / 256;
  const int FB = (iters + 63) / 64;
  const int NB = (N + 255) / 256;  // 64 partial-blocks

  // workspace layout (16B-aligned start; float2 then doubles keeps 8B align)
  float2* P1 = (float2*)d_ws;                        // N float2
  float2* P2 = P1 + N;                               // N float2
  double* partials = (double*)(P2 + N);              // NB*48 doubles
  double* meanout = partials + (size_t)NB * 48;      // 8 doubles
  float* models = (float*)(meanout + 8);             // iters*9
  float* ml = models + (size_t)iters * 9;            // iters
  float* ssum = ml + iters;                          // iters
  int* uniq = (int*)(ssum + iters);                  // iters

  float* outF = (float*)d_out;  // 9 floats (Mbest)
  float* outmask = outF + 9;    // N floats (0/1)

  prep_and_fit<<<TB + FB, 256, 0, stream>>>(pts1, pts2, samples, P1, P2,
                                            models, uniq, N, iters, TB);
  sampson_stats4<<<(iters + 3) / 4, 256, 0, stream>>>(P1, P2, models, ml, ssum,
                                                      N, iters);
  selmask_part<<<NB, 256, 0, stream>>>(P1, P2, models, ml, ssum, uniq,
                                       outmask, partials, meanout, N, iters);
  ff_solve<<<1, 64, 0, stream>>>(partials, meanout, outF, NB);
}

// Round 17
// 177.796 us; speedup vs baseline: 1.2385x; 1.0283x over previous
//
#include <hip/hip_runtime.h>
#include <math.h>
#include <type_traits>
#include <utility>

#if defined(__has_builtin)
#if __has_builtin(__builtin_amdgcn_rcpf)
#define FAST_RCPF(x) __builtin_amdgcn_rcpf(x)
#endif
#if __has_builtin(__builtin_amdgcn_rsqf)
#define FAST_RSQF(x) __builtin_amdgcn_rsqf(x)
#endif
#endif
#ifndef FAST_RCPF
#define FAST_RCPF(x) (1.0f / (x))
#endif
#ifndef FAST_RSQF
#define FAST_RSQF(x) (1.0f / sqrtf(x))
#endif

// packed lower-tri index (constexpr -> folds in templates)
__host__ __device__ constexpr int PIX(int i, int j) { return i * (i + 1) / 2 + j; }

// ============================================================
// RULES (hard-won):
//  R6/R7: SROA runs before unrolling, never re-runs -> template-constant
//         indices only for per-thread arrays.
//  R9/R11: a kernel holding a 45-double per-thread accumulator must be
//         dedicated+simple (streaming path here has none -- 1 pt/thread).
//  R13:  no mixed packed/scalar f32 dataflow (LDS spill).
//  R14:  sampson: 4 models/block sweet spot; not occupancy-bound.
//  R15:  global f64 atomics many-waves->few-addresses serialize ~0.4us ea;
//        soft grid barriers cost >> a 20us dispatch boundary.
//  R16:  a redundant full-N loop at VGPR=24 has zero load pipelining ->
//        52us of pure latency. Fix: launch_bounds(,1) + manual 4x load
//        batching (8 outstanding loads/iter).
// ============================================================
template <int N, int I = 0, typename F>
__device__ __forceinline__ void static_for(F&& f) {
  if constexpr (I < N) {
    f(std::integral_constant<int, I>{});
    static_for<N, I + 1>(static_cast<F&&>(f));
  }
}

// ---------- 9x9 packed Cholesky, template-indexed ----------
template <int I, int J, int K>
__device__ __forceinline__ double csub9(const double* M, double s) {
  if constexpr (K >= J) return s;
  else return csub9<I, J, K + 1>(M, s - M[PIX(I, K)] * M[PIX(J, K)]);
}
template <int I, int J>
__device__ __forceinline__ void cholJ(double* M) {
  if constexpr (J <= I) {
    double s = csub9<I, J, 0>(M, M[PIX(I, J)]);
    if constexpr (J == I)
      M[PIX(I, I)] = sqrt(fmax(s, 1e-300));
    else
      M[PIX(I, J)] = s / M[PIX(J, J)];
    cholJ<I, J + 1>(M);
  }
}
template <int I>
__device__ __forceinline__ void cholI(double* M) {
  if constexpr (I < 9) {
    cholJ<I, 0>(M);
    cholI<I + 1>(M);
  }
}

// ---------- forward/backward substitution, template-indexed ----------
template <int I, int K>
__device__ __forceinline__ double fsub9(const double* L, const double* x, double s) {
  if constexpr (K >= I) return s;
  else return fsub9<I, K + 1>(L, x, s - L[PIX(I, K)] * x[K]);
}
template <int I>
__device__ __forceinline__ void fwd9(const double* L, double* x) {
  if constexpr (I < 9) {
    x[I] = fsub9<I, 0>(L, x, x[I]) / L[PIX(I, I)];
    fwd9<I + 1>(L, x);
  }
}
template <int I, int K>
__device__ __forceinline__ double bsub9(const double* L, const double* x, double s) {
  if constexpr (K >= 9) return s;
  else return bsub9<I, K + 1>(L, x, s - L[PIX(K, I)] * x[K]);
}
template <int I>
__device__ __forceinline__ void bwd9(const double* L, double* x) {
  if constexpr (I >= 0) {
    x[I] = bsub9<I, I + 1>(L, x, x[I]) / L[PIX(I, I)];
    bwd9<I - 1>(L, x);
  }
}

// ---------- AtA rank-1 update (fit kernel only) ----------
template <int I, int J>
__device__ __forceinline__ void ataIJ(double* M, const double (&a)[9], double w) {
  if constexpr (J <= I) {
    M[PIX(I, J)] += w * a[I] * a[J];
    ataIJ<I, J + 1>(M, a, w);
  }
}
template <int I>
__device__ __forceinline__ void ataI(double* M, const double (&a)[9], double w) {
  if constexpr (I < 9) {
    ataIJ<I, 0>(M, a, w);
    ataI<I + 1>(M, a, w);
  }
}

// ---------- 3x3 Jacobi rotation on named scalars ----------
#define JROT(P, Q)                                                              \
  {                                                                             \
    double apq = a##P##Q;                                                       \
    if (fabs(apq) >= 1e-300) {                                                  \
      double tau = (a##Q##Q - a##P##P) / (2.0 * apq);                           \
      double t = ((tau >= 0.0) ? 1.0 : -1.0) / (fabs(tau) + sqrt(1.0 + tau * tau)); \
      double c = 1.0 / sqrt(1.0 + t * t);                                       \
      double s = t * c;                                                         \
      double t0p = a0##P, t0q = a0##Q;                                          \
      a0##P = c * t0p - s * t0q; a0##Q = s * t0p + c * t0q;                     \
      double t1p = a1##P, t1q = a1##Q;                                          \
      a1##P = c * t1p - s * t1q; a1##Q = s * t1p + c * t1q;                     \
      double t2p = a2##P, t2q = a2##Q;                                          \
      a2##P = c * t2p - s * t2q; a2##Q = s * t2p + c * t2q;                     \
      double rp0 = a##P##0, rq0 = a##Q##0;                                      \
      a##P##0 = c * rp0 - s * rq0; a##Q##0 = s * rp0 + c * rq0;                 \
      double rp1 = a##P##1, rq1 = a##Q##1;                                      \
      a##P##1 = c * rp1 - s * rq1; a##Q##1 = s * rp1 + c * rq1;                 \
      double rp2 = a##P##2, rq2 = a##Q##2;                                      \
      a##P##2 = c * rp2 - s * rq2; a##Q##2 = s * rp2 + c * rq2;                 \
      double u0p = V0##P, u0q = V0##Q;                                          \
      V0##P = c * u0p - s * u0q; V0##Q = s * u0p + c * u0q;                     \
      double u1p = V1##P, u1q = V1##Q;                                          \
      V1##P = c * u1p - s * u1q; V1##Q = s * u1p + c * u1q;                     \
      double u2p = V2##P, u2q = V2##Q;                                          \
      V2##P = c * u2p - s * u2q; V2##Q = s * u2p + c * u2q;                     \
    }                                                                           \
  }

// ---------- full solver: null vec of AtA -> rank-2 -> denormalize ----------
__device__ __forceinline__ void solveF(double* M, double s1, double m1x, double m1y,
                                       double s2, double m2x, double m2y,
                                       float* out) {
  double tr = M[0] + M[2] + M[5] + M[9] + M[14] + M[20] + M[27] + M[35] + M[44];
  double shift = 1e-12 * tr;
  M[0] += shift; M[2] += shift; M[5] += shift; M[9] += shift; M[14] += shift;
  M[20] += shift; M[27] += shift; M[35] += shift; M[44] += shift;
  cholI<0>(M);
  double x[9];
  static_for<9>([&](auto i) { x[i] = 1.0; });
  static_for<3>([&](auto) {
    fwd9<0>(M, x);
    bwd9<8>(M, x);
    double n = 0.0;
    static_for<9>([&](auto i) { n += x[i] * x[i]; });
    n = 1.0 / sqrt(n);
    static_for<9>([&](auto i) { x[i] *= n; });
  });
  const double g00 = x[0] * x[0] + x[3] * x[3] + x[6] * x[6];
  const double g01 = x[0] * x[1] + x[3] * x[4] + x[6] * x[7];
  const double g02 = x[0] * x[2] + x[3] * x[5] + x[6] * x[8];
  const double g11 = x[1] * x[1] + x[4] * x[4] + x[7] * x[7];
  const double g12 = x[1] * x[2] + x[4] * x[5] + x[7] * x[8];
  const double g22 = x[2] * x[2] + x[5] * x[5] + x[8] * x[8];
  double a00 = g00, a01 = g01, a02 = g02;
  double a10 = g01, a11 = g11, a12 = g12;
  double a20 = g02, a21 = g12, a22 = g22;
  double V00 = 1, V01 = 0, V02 = 0;
  double V10 = 0, V11 = 1, V12 = 0;
  double V20 = 0, V21 = 0, V22 = 1;
  for (int sweep = 0; sweep < 6; ++sweep) {
    JROT(0, 1);
    JROT(0, 2);
    JROT(1, 2);
  }
  double mv = a00, v0 = V00, v1 = V10, v2 = V20;
  if (a11 < mv) { mv = a11; v0 = V01; v1 = V11; v2 = V21; }
  if (a22 < mv) { mv = a22; v0 = V02; v1 = V12; v2 = V22; }
  const double fv0 = x[0] * v0 + x[1] * v1 + x[2] * v2;
  const double fv1 = x[3] * v0 + x[4] * v1 + x[5] * v2;
  const double fv2 = x[6] * v0 + x[7] * v1 + x[8] * v2;
  const double F200 = x[0] - fv0 * v0, F201 = x[1] - fv0 * v1, F202 = x[2] - fv0 * v2;
  const double F210 = x[3] - fv1 * v0, F211 = x[4] - fv1 * v1, F212 = x[5] - fv1 * v2;
  const double F220 = x[6] - fv2 * v0, F221 = x[7] - fv2 * v1, F222 = x[8] - fv2 * v2;
  const double R00 = s2 * F200, R01 = s2 * F201, R02 = s2 * F202;
  const double R10 = s2 * F210, R11 = s2 * F211, R12 = s2 * F212;
  const double R20 = -s2 * m2x * F200 - s2 * m2y * F210 + F220;
  const double R21 = -s2 * m2x * F201 - s2 * m2y * F211 + F221;
  const double R22 = -s2 * m2x * F202 - s2 * m2y * F212 + F222;
  const double Ff00 = s1 * R00, Ff01 = s1 * R01;
  const double Ff02 = -s1 * m1x * R00 - s1 * m1y * R01 + R02;
  const double Ff10 = s1 * R10, Ff11 = s1 * R11;
  const double Ff12 = -s1 * m1x * R10 - s1 * m1y * R11 + R12;
  const double Ff20 = s1 * R20, Ff21 = s1 * R21;
  const double Ff22 = -s1 * m1x * R20 - s1 * m1y * R21 + R22;
  const double inv = 1.0 / Ff22;
  out[0] = (float)(Ff00 * inv); out[1] = (float)(Ff01 * inv); out[2] = (float)(Ff02 * inv);
  out[3] = (float)(Ff10 * inv); out[4] = (float)(Ff11 * inv); out[5] = (float)(Ff12 * inv);
  out[6] = (float)(Ff20 * inv); out[7] = (float)(Ff21 * inv); out[8] = (float)(Ff22 * inv);
}

// ============================================================
// Sampson terms (z==1.0 exactly; elision is bit-identical)
// ============================================================
struct F9 {
  float f0, f1, f2, f3, f4, f5, f6, f7, f8;
};

__device__ __forceinline__ F9 loadF(const float* __restrict__ p) {
  F9 F;
  F.f0 = p[0]; F.f1 = p[1]; F.f2 = p[2];
  F.f3 = p[3]; F.f4 = p[4]; F.f5 = p[5];
  F.f6 = p[6]; F.f7 = p[7]; F.f8 = p[8];
  return F;
}

__device__ __forceinline__ void samp_numden(const F9& F, float px, float py,
                                            float qx, float qy, float& num,
                                            float& den, float& dout) {
  float a0 = fmaf(F.f0, px, fmaf(F.f1, py, F.f2));
  float a1 = fmaf(F.f3, px, fmaf(F.f4, py, F.f5));
  float a2 = fmaf(F.f6, px, fmaf(F.f7, py, F.f8));
  float b0 = fmaf(F.f0, qx, fmaf(F.f3, qy, F.f6));
  float b1 = fmaf(F.f1, qx, fmaf(F.f4, qy, F.f7));
  float d = fmaf(qx, a0, fmaf(qy, a1, a2));
  num = d * d;
  den = fmaf(a0, a0, fmaf(a1, a1, fmaf(b0, b0, b1 * b1)));
  dout = d;
}

// predicate num<=den is EXACT (same every round); sqrt(err) = |d|*rsqrt(den).
__device__ __forceinline__ void samp_acc(const F9& F, float px, float py,
                                         float qx, float qy, float& cnt,
                                         float& ss) {
  float num, den, d;
  samp_numden(F, px, py, qx, qy, num, den, d);
  const bool in = (num <= den);
  const float val = fabsf(d) * FAST_RSQF(den);
  cnt += in ? 1.0f : 0.0f;
  ss += in ? val : 0.0f;
}

// mean-sum accumulate (f64) for the redundant mean pass
__device__ __forceinline__ void mean_acc(const F9& F, float2 p, float2 q,
                                         double& sw, double& spx, double& spy,
                                         double& sqx, double& sqy) {
  float num, den, dd;
  samp_numden(F, p.x, p.y, q.x, q.y, num, den, dd);
  if (num <= den) {
    sw += 1.0;
    spx += (double)p.x;
    spy += (double)p.y;
    sqx += (double)q.x;
    sqy += (double)q.y;
  }
}

// ============================================================
// Kernel 1: transpose blocks [0,TB) (float2 x,y) + fit blocks [TB,..)
// ============================================================
__global__ __launch_bounds__(256, 1) void prep_and_fit(
    const float* __restrict__ pts1, const float* __restrict__ pts2,
    const int* __restrict__ samples, float2* __restrict__ P1,
    float2* __restrict__ P2, float* __restrict__ models,
    int* __restrict__ uflag, int N, int iters, int TB) {
  if ((int)blockIdx.x < TB) {
    const int i = blockIdx.x * 256 + threadIdx.x;
    if (i < N) {
      P1[i] = make_float2(pts1[3 * i], pts1[3 * i + 1]);
      P2[i] = make_float2(pts2[3 * i], pts2[3 * i + 1]);
    }
    return;
  }
  if (threadIdx.x >= 64) return;
  const int it = (blockIdx.x - TB) * 64 + threadIdx.x;
  if (it >= iters) return;

  int idx[8];
  static_for<8>([&](auto k) { idx[k] = samples[it * 8 + k]; });
  int u = 1;
  static_for<8>([&](auto A) {
    static_for<8>([&](auto B) {
      if constexpr (decltype(B)::value > decltype(A)::value) {
        if (idx[A] == idx[B]) u = 0;
      }
    });
  });
  uflag[it] = u;

  float X1[8], Y1[8], Z1[8], X2[8], Y2[8], Z2[8];
  static_for<8>([&](auto k) {
    const int j = idx[k];
    X1[k] = pts1[3 * j]; Y1[k] = pts1[3 * j + 1]; Z1[k] = pts1[3 * j + 2];
    X2[k] = pts2[3 * j]; Y2[k] = pts2[3 * j + 1]; Z2[k] = pts2[3 * j + 2];
  });
  double sx1 = 0, sy1 = 0, sx2 = 0, sy2 = 0;
  static_for<8>([&](auto k) {
    sx1 += (double)X1[k]; sy1 += (double)Y1[k];
    sx2 += (double)X2[k]; sy2 += (double)Y2[k];
  });
  const double m1x = sx1 / 8.0, m1y = sy1 / 8.0;
  const double m2x = sx2 / 8.0, m2y = sy2 / 8.0;
  double sd1 = 0, sd2 = 0;
  static_for<8>([&](auto k) {
    double dx1 = (double)X1[k] - m1x, dy1 = (double)Y1[k] - m1y;
    double dx2 = (double)X2[k] - m2x, dy2 = (double)Y2[k] - m2y;
    sd1 += sqrt(dx1 * dx1 + dy1 * dy1);
    sd2 += sqrt(dx2 * dx2 + dy2 * dy2);
  });
  const double s1 = sqrt(2.0) / (sd1 / 8.0 + 1e-8);
  const double s2 = sqrt(2.0) / (sd2 / 8.0 + 1e-8);

  double M[45];
  static_for<45>([&](auto r) { M[r] = 0.0; });
  static_for<8>([&](auto k) {
    const double z1 = (double)Z1[k], z2 = (double)Z2[k];
    const double p1x = s1 * ((double)X1[k] - m1x * z1);
    const double p1y = s1 * ((double)Y1[k] - m1y * z1);
    const double p2x = s2 * ((double)X2[k] - m2x * z2);
    const double p2y = s2 * ((double)Y2[k] - m2y * z2);
    const double a[9] = {p2x * p1x, p2x * p1y, p2x * z1,
                         p2y * p1x, p2y * p1y, p2y * z1,
                         z2 * p1x,  z2 * p1y,  z2 * z1};
    ataI<0>(M, a, 1.0);
  });
  solveF(M, s1, m1x, m1y, s2, m2x, m2y, models + (size_t)it * 9);
}

// ============================================================
// Kernel 2: 4 models/block (R12-proven: 43.4us), float2 loads
// ============================================================
__global__ __launch_bounds__(256, 4) void sampson_stats4(
    const float2* __restrict__ P1, const float2* __restrict__ P2,
    const float* __restrict__ models, float* __restrict__ ml,
    float* __restrict__ ssum, int N, int iters) {
  const int m0 = blockIdx.x * 4;
  const int c0 = min(m0 + 0, iters - 1), c1 = min(m0 + 1, iters - 1);
  const int c2 = min(m0 + 2, iters - 1), c3 = min(m0 + 3, iters - 1);
  const F9 Fa = loadF(models + (size_t)c0 * 9);
  const F9 Fb = loadF(models + (size_t)c1 * 9);
  const F9 Fc = loadF(models + (size_t)c2 * 9);
  const F9 Fd = loadF(models + (size_t)c3 * 9);
  float ca = 0, cb = 0, cc = 0, cd = 0;
  float sa = 0, sb = 0, sc_ = 0, sd = 0;
  const int NP = N & ~511;
  for (int i = threadIdx.x; i < NP; i += 512) {
    const float2 pA = P1[i];
    const float2 qA = P2[i];
    const float2 pB = P1[i + 256];
    const float2 qB = P2[i + 256];
    samp_acc(Fa, pA.x, pA.y, qA.x, qA.y, ca, sa);
    samp_acc(Fb, pA.x, pA.y, qA.x, qA.y, cb, sb);
    samp_acc(Fc, pA.x, pA.y, qA.x, qA.y, cc, sc_);
    samp_acc(Fd, pA.x, pA.y, qA.x, qA.y, cd, sd);
    samp_acc(Fa, pB.x, pB.y, qB.x, qB.y, ca, sa);
    samp_acc(Fb, pB.x, pB.y, qB.x, qB.y, cb, sb);
    samp_acc(Fc, pB.x, pB.y, qB.x, qB.y, cc, sc_);
    samp_acc(Fd, pB.x, pB.y, qB.x, qB.y, cd, sd);
  }
  for (int i = NP + threadIdx.x; i < N; i += 256) {
    const float2 p = P1[i];
    const float2 q = P2[i];
    samp_acc(Fa, p.x, p.y, q.x, q.y, ca, sa);
    samp_acc(Fb, p.x, p.y, q.x, q.y, cb, sb);
    samp_acc(Fc, p.x, p.y, q.x, q.y, cc, sc_);
    samp_acc(Fd, p.x, p.y, q.x, q.y, cd, sd);
  }
  __shared__ float shc[4][4], shs[4][4];
  const int lane = threadIdx.x & 63, wv = threadIdx.x >> 6;
  float c4[4] = {ca, cb, cc, cd};
  float s4[4] = {sa, sb, sc_, sd};
  static_for<4>([&](auto m) {
    float c = c4[m], s = s4[m];
#pragma unroll
    for (int o = 32; o > 0; o >>= 1) {
      c += __shfl_down(c, o);
      s += __shfl_down(s, o);
    }
    if (lane == 0) { shc[wv][m] = c; shs[wv][m] = s; }
  });
  __syncthreads();
  if (threadIdx.x < 4 && m0 + threadIdx.x < iters) {
    const int m = threadIdx.x;
    ml[m0 + m] = shc[0][m] + shc[1][m] + shc[2][m] + shc[3][m];
    ssum[m0 + m] = shs[0][m] + shs[1][m] + shs[2][m] + shs[3][m];
  }
}

// ============================================================
// Kernel 3: select (redundant/block) + REDUNDANT full-N means with 4x
// load batching (R16 lesson: unbatched at VGPR=24 = 52us pure latency) +
// own-slice mask + centered AtA partials. ZERO global atomics.
// partials[b*48 + k]: k=0..44 AtA, 45=sd1, 46=sd2 (plain stores).
// Block 0 additionally stores means to meanout[0..4].
// ============================================================
__global__ __launch_bounds__(256, 1) void selmask_part(
    const float2* __restrict__ P1, const float2* __restrict__ P2,
    const float* __restrict__ models, const float* __restrict__ ml,
    const float* __restrict__ ssum, const int* __restrict__ uniq,
    float* __restrict__ outmask, double* __restrict__ partials,
    double* __restrict__ meanout, int N, int iters) {
  const int tid = threadIdx.x;
  const int lane = tid & 63, wv = tid >> 6;
  __shared__ float ra[256], rb[256];
  __shared__ int rid[256];
  // ---- phase A: select_best (identical math every round)
  float mlmax = 0.f, mnmax = -INFINITY;
  for (int i = tid; i < iters; i += 256) {
    if (uniq[i]) {
      float m = ml[i];
      mlmax = fmaxf(mlmax, m);
      float mean = (ssum[i] + 1e-8f) / (m + 1e-8f);
      mnmax = fmaxf(mnmax, mean);
    }
  }
  ra[tid] = mlmax;
  rb[tid] = mnmax;
  __syncthreads();
  for (int s = 128; s > 0; s >>= 1) {
    if (tid < s) {
      ra[tid] = fmaxf(ra[tid], ra[tid + s]);
      rb[tid] = fmaxf(rb[tid], rb[tid + s]);
    }
    __syncthreads();
  }
  const float MLMAX = ra[0];
  const float MNMAX = rb[0];
  __syncthreads();
  float bsc = -INFINITY;
  int bid = 0x7FFFFFFF;
  for (int i = tid; i < iters; i += 256) {
    float sc = -INFINITY;
    float m = ml[i];
    float mean = (ssum[i] + 1e-8f) / (m + 1e-8f);
    if (uniq[i]) sc = 0.5f * (m / MLMAX) + 0.5f * (1.0f - mean / MNMAX);
    if (sc > bsc || (sc == bsc && i < bid)) { bsc = sc; bid = i; }
  }
  ra[tid] = bsc;
  rid[tid] = bid;
  __syncthreads();
  for (int s = 128; s > 0; s >>= 1) {
    if (tid < s) {
      if (ra[tid + s] > ra[tid] ||
          (ra[tid + s] == ra[tid] && rid[tid + s] < rid[tid])) {
        ra[tid] = ra[tid + s];
        rid[tid] = rid[tid + s];
      }
    }
    __syncthreads();
  }
  const int best = rid[0];
  const F9 F = loadF(models + (size_t)best * 9);

  // ---- phase B: REDUNDANT full-N mean sums, 4x batched loads (8
  // outstanding float2 loads per iteration -> latency/8). Same order in
  // every block -> bitwise-identical means; no cross-block communication.
  __shared__ double sm[5][4];
  double sw = 0, spx = 0, spy = 0, sqx = 0, sqy = 0;
  const int NB4 = N & ~1023;
  for (int i = tid; i < NB4; i += 1024) {
    const float2 pa = P1[i];
    const float2 pb = P1[i + 256];
    const float2 pc = P1[i + 512];
    const float2 pd = P1[i + 768];
    const float2 qa = P2[i];
    const float2 qb = P2[i + 256];
    const float2 qc = P2[i + 512];
    const float2 qd = P2[i + 768];
    mean_acc(F, pa, qa, sw, spx, spy, sqx, sqy);
    mean_acc(F, pb, qb, sw, spx, spy, sqx, sqy);
    mean_acc(F, pc, qc, sw, spx, spy, sqx, sqy);
    mean_acc(F, pd, qd, sw, spx, spy, sqx, sqy);
  }
  for (int i = NB4 + tid; i < N; i += 256) {
    mean_acc(F, P1[i], P2[i], sw, spx, spy, sqx, sqy);
  }
  {
    double v0 = sw, v1 = spx, v2 = spy, v3 = sqx, v4 = sqy;
#pragma unroll
    for (int o = 32; o > 0; o >>= 1) {
      v0 += __shfl_down(v0, o); v1 += __shfl_down(v1, o);
      v2 += __shfl_down(v2, o); v3 += __shfl_down(v3, o);
      v4 += __shfl_down(v4, o);
    }
    if (lane == 0) {
      sm[0][wv] = v0; sm[1][wv] = v1; sm[2][wv] = v2;
      sm[3][wv] = v3; sm[4][wv] = v4;
    }
  }
  __syncthreads();
  const double WS = sm[0][0] + sm[0][1] + sm[0][2] + sm[0][3];
  const double M1X = (sm[1][0] + sm[1][1] + sm[1][2] + sm[1][3]) / WS;
  const double M1Y = (sm[2][0] + sm[2][1] + sm[2][2] + sm[2][3]) / WS;
  const double M2X = (sm[3][0] + sm[3][1] + sm[3][2] + sm[3][3]) / WS;
  const double M2Y = (sm[4][0] + sm[4][1] + sm[4][2] + sm[4][3]) / WS;
  if (blockIdx.x == 0 && tid == 0) {
    meanout[0] = WS;
    meanout[1] = M1X; meanout[2] = M1Y;
    meanout[3] = M2X; meanout[4] = M2Y;
  }
  __syncthreads();

  // ---- phase C: own point -> mask + centered terms; block-reduce 47
  // values into partials (plain stores, no atomics).
  const int i = blockIdx.x * 256 + tid;
  double u0 = 0, u1 = 0, v0 = 0, v1 = 0, a8 = 0, sd1 = 0, sd2 = 0;
  if (i < N) {
    const float2 p = P1[i];
    const float2 q = P2[i];
    float num, den, dd;
    samp_numden(F, p.x, p.y, q.x, q.y, num, den, dd);
    const bool in = (num <= den);  // same predicate as sampson_stats4
    outmask[i] = in ? 1.0f : 0.0f;
    if (in) {
      v0 = (double)p.x - M1X; v1 = (double)p.y - M1Y;
      u0 = (double)q.x - M2X; u1 = (double)q.y - M2Y;
      a8 = 1.0;
      sd1 = sqrt(v0 * v0 + v1 * v1);
      sd2 = sqrt(u0 * u0 + u1 * u1);
    }
  }
  const double a[9] = {u0 * v0, u0 * v1, u0, u1 * v0, u1 * v1, u1, v0, v1, a8};
  __shared__ double red[47][4];
  static_for<9>([&](auto I_) {
    static_for<9>([&](auto J_) {
      constexpr int ii = decltype(I_)::value;
      constexpr int jj = decltype(J_)::value;
      if constexpr (jj <= ii) {
        double v = a[ii] * a[jj];
#pragma unroll
        for (int o = 32; o > 0; o >>= 1) v += __shfl_down(v, o);
        if (lane == 0) red[PIX(ii, jj)][wv] = v;
      }
    });
  });
  {
    double t1 = sd1, t2 = sd2;
#pragma unroll
    for (int o = 32; o > 0; o >>= 1) {
      t1 += __shfl_down(t1, o);
      t2 += __shfl_down(t2, o);
    }
    if (lane == 0) { red[45][wv] = t1; red[46][wv] = t2; }
  }
  __syncthreads();
  if (tid < 47) {
    partials[(size_t)blockIdx.x * 48 + tid] =
        red[tid][0] + red[tid][1] + red[tid][2] + red[tid][3];
  }
}

// ============================================================
// Kernel 4: reduce partials (47 threads x NB plain reads, deterministic
// order) then thread 0 applies D*M*D + solver (dedicated -> registerizes).
// ============================================================
__global__ __launch_bounds__(64, 1) void ff_solve(
    const double* __restrict__ partials, const double* __restrict__ meanout,
    float* __restrict__ outF, int NB) {
  if (blockIdx.x != 0) return;
  __shared__ double red[47];
  if (threadIdx.x < 47) {
    double s = 0.0;
    for (int b = 0; b < NB; ++b) s += partials[(size_t)b * 48 + threadIdx.x];
    red[threadIdx.x] = s;
  }
  __syncthreads();
  if (threadIdx.x != 0) return;
  const double WS = meanout[0];
  const double M1X = meanout[1], M1Y = meanout[2];
  const double M2X = meanout[3], M2Y = meanout[4];
  const double S1 = sqrt(2.0) / (red[45] / WS + 1e-8);
  const double S2 = sqrt(2.0) / (red[46] / WS + 1e-8);
  double M[45];
  static_for<45>([&](auto r) { M[r] = red[r]; });
  // apply D * M * D, D_(3r+c) = S2^[r<2] * S1^[c<2]
  static_for<9>([&](auto I_) {
    static_for<9>([&](auto J_) {
      constexpr int i = decltype(I_)::value;
      constexpr int j = decltype(J_)::value;
      if constexpr (j <= i) {
        const double sr = ((i / 3) < 2 ? S2 : 1.0) * ((i % 3) < 2 ? S1 : 1.0);
        const double sc = ((j / 3) < 2 ? S2 : 1.0) * ((j % 3) < 2 ? S1 : 1.0);
        M[PIX(i, j)] *= sr * sc;
      }
    });
  });
  solveF(M, S1, M1X, M1Y, S2, M2X, M2Y, outF);
}

// ============================================================
// Host launcher — 4 dispatches, zero atomics, zero barriers
// ============================================================
extern "C" void kernel_launch(void* const* d_in, const int* in_sizes, int n_in,
                              void* d_out, int out_size, void* d_ws, size_t ws_size,
                              hipStream_t stream) {
  const float* pts1 = (const float*)d_in[0];
  const float* pts2 = (const float*)d_in[1];
  const int* samples = (const int*)d_in[2];
  const int N = in_sizes[0] / 3;      // 16384
  const int iters = in_sizes[2] / 8;  // 4096

  const int TB = (N + 255) / 256;
  const int FB = (iters + 63) / 64;
  const int NB = (N + 255) / 256;  // 64 partial-blocks

  // workspace layout (16B-aligned start; float2 then doubles keeps 8B align)
  float2* P1 = (float2*)d_ws;                        // N float2
  float2* P2 = P1 + N;                               // N float2
  double* partials = (double*)(P2 + N);              // NB*48 doubles
  double* meanout = partials + (size_t)NB * 48;      // 8 doubles
  float* models = (float*)(meanout + 8);             // iters*9
  float* ml = models + (size_t)iters * 9;            // iters
  float* ssum = ml + iters;                          // iters
  int* uniq = (int*)(ssum + iters);                  // iters

  float* outF = (float*)d_out;  // 9 floats (Mbest)
  float* outmask = outF + 9;    // N floats (0/1)

  prep_and_fit<<<TB + FB, 256, 0, stream>>>(pts1, pts2, samples, P1, P2,
                                            models, uniq, N, iters, TB);
  sampson_stats4<<<(iters + 3) / 4, 256, 0, stream>>>(P1, P2, models, ml, ssum,
                                                      N, iters);
  selmask_part<<<NB, 256, 0, stream>>>(P1, P2, models, ml, ssum, uniq,
                                       outmask, partials, meanout, N, iters);
  ff_solve<<<1, 64, 0, stream>>>(partials, meanout, outF, NB);
}